// Round 8
// baseline (212.982 us; speedup 1.0000x reference)
//
#include <hip/hip_runtime.h>
#include <hip/hip_bf16.h>
#include <math.h>

#define BB 4
#define SS 2048
#define HH 768
#define NH 12
#define HD 64
#define MROWS (BB*SS)   // 8192

typedef __attribute__((ext_vector_type(8))) short bf16x8;
typedef __attribute__((ext_vector_type(4))) float f32x4;
typedef _Float16 half8 __attribute__((ext_vector_type(8)));
typedef __fp16 fp16x2 __attribute__((ext_vector_type(2)));   // cvt_pkrtz result type

#define LDS_CAST(p) ((__attribute__((address_space(3))) void*)(p))
#define GLB_CAST(p) ((const __attribute__((address_space(1))) void*)(p))

#define LOG2E 1.442695040889f

// fast 2^x: single v_exp_f32, NOT the precise OCML exp2f library call
static __device__ __forceinline__ float fast_exp2(float x) {
#if __has_builtin(__builtin_amdgcn_exp2f)
    return __builtin_amdgcn_exp2f(x);
#else
    float r;
    asm("v_exp_f32 %0, %1" : "=v"(r) : "v"(x));
    return r;
#endif
}

static __device__ __forceinline__ ushort f2bf(float f) {
    union { float f; unsigned u; } c; c.f = f;
    unsigned u = c.u;
    return (ushort)((u + 0x7fffu + ((u >> 16) & 1u)) >> 16);
}

// ---------------------------------------------------------------------------
// Kernel 0: fp32 -> bf16 one-shot conversion of X, Wq, Wk, Wv.
// ---------------------------------------------------------------------------
#define XCH  786432u   // 6291456/8
#define WCH  73728u    // 589824/8
__global__ __launch_bounds__(256) void cvt_kernel(
    const float* __restrict__ X,  const float* __restrict__ Wq,
    const float* __restrict__ Wk, const float* __restrict__ Wv,
    ushort* __restrict__ Xb, ushort* __restrict__ Wqb,
    ushort* __restrict__ Wkb, ushort* __restrict__ Wvb)
{
    unsigned c = blockIdx.x * 256 + threadIdx.x;
    const float* src; ushort* dst; size_t idx;
    if (c < XCH) { src = X; dst = Xb; idx = c; }
    else {
        unsigned c2 = c - XCH;
        unsigned w = c2 / WCH, i2 = c2 - w * WCH;
        src = (w == 0) ? Wq : (w == 1) ? Wk : Wv;
        dst = (w == 0) ? Wqb : (w == 1) ? Wkb : Wvb;
        idx = i2;
    }
    size_t e = idx * 8;
    float4 a = *(const float4*)(src + e);
    float4 b = *(const float4*)(src + e + 4);
    unsigned p0 = f2bf(a.x) | ((unsigned)f2bf(a.y) << 16);
    unsigned p1 = f2bf(a.z) | ((unsigned)f2bf(a.w) << 16);
    unsigned p2 = f2bf(b.x) | ((unsigned)f2bf(b.y) << 16);
    unsigned p3 = f2bf(b.z) | ((unsigned)f2bf(b.w) << 16);
    *(int4*)(dst + e) = make_int4((int)p0, (int)p1, (int)p2, (int)p3);
}

// ---------------------------------------------------------------------------
// Kernel 1: QKV projection, 128x128 tile.  R7: fattn-style DOUBLE-BUFFERED
// K-loop (one barrier per 64-K slice, guarded prefetch, compile-time buffer
// indices) replacing the 2-barrier m97 structure.  XOR-swizzled LDS.
// Q: bf16 [bh][s][d] pre-scaled by 0.125*log2e.  K: bf16 [bh][s][d].
// V: fp16 [bh][d][s], keys pre-permuted within 64-groups.
// ---------------------------------------------------------------------------
__global__ __launch_bounds__(256) void qkv_mfma(
    const ushort* __restrict__ Xb,
    const ushort* __restrict__ Wqb, const ushort* __restrict__ Wkb,
    const ushort* __restrict__ Wvb,
    const float* __restrict__ bq, const float* __restrict__ bk,
    const float* __restrict__ bv,
    ushort* __restrict__ Qo, ushort* __restrict__ Ko, ushort* __restrict__ Vt)
{
    // XCD-swizzled decode: 1152 = 8 xcd * 8 mt * (6 nt * 3 z)
    const int id = blockIdx.x;
    const int xcd = id & 7, sub = id >> 3;        // sub: 0..143
    const int mt = xcd * 8 + (sub & 7);           // 0..63
    const int rest = sub >> 3;                    // 0..17
    const int nt = rest % 6, z = rest / 6;

    const ushort* W    = (z == 0) ? Wqb : (z == 1) ? Wkb : Wvb;
    const float*  bias = (z == 0) ? bq  : (z == 1) ? bk  : bv;

    __shared__ ushort Xs[2][128 * 64];
    __shared__ ushort Ws2[2][128 * 64];

    const int tid = threadIdx.x;
    const int w = tid >> 6, lane = tid & 63, quad = lane >> 4, l15 = lane & 15;
    const int m0 = mt * 128, n0 = nt * 128;
    const int r0 = (w >> 1) * 64, c0 = (w & 1) * 64;

    const int lrow   = lane >> 3;                 // 0..7
    const int lchunk = (lane & 7) ^ lrow;         // logical 16B-chunk
    const ushort* gX = Xb + (size_t)(m0 + w * 32 + lrow) * HH + lchunk * 8;
    const ushort* gW = W  + (size_t)(n0 + w * 32 + lrow) * HH + lchunk * 8;

    f32x4 acc[4][4];
#pragma unroll
    for (int i = 0; i < 4; i++)
#pragma unroll
        for (int j = 0; j < 4; j++) acc[i][j] = (f32x4){0.f, 0.f, 0.f, 0.f};

    // stage one 64-K slice (X + W tiles) into buffer `buf`
    auto stage = [&](int kt, int buf) {
#pragma unroll
        for (int j = 0; j < 4; j++) {
            __builtin_amdgcn_global_load_lds(GLB_CAST(gX + kt + (size_t)j * 8 * HH),
                                             LDS_CAST(Xs[buf]  + w * 2048 + j * 512), 16, 0, 0);
            __builtin_amdgcn_global_load_lds(GLB_CAST(gW + kt + (size_t)j * 8 * HH),
                                             LDS_CAST(Ws2[buf] + w * 2048 + j * 512), 16, 0, 0);
        }
    };

    // consume one 64-K slice from buffer `buf`
    auto compute = [&](int buf) {
#pragma unroll
        for (int kh = 0; kh < 2; kh++) {
            bf16x8 a[4], bfr[4];
#pragma unroll
            for (int i = 0; i < 4; i++) {
                const int ra = r0 + 16 * i + l15;
                const int rb = c0 + 16 * i + l15;
                const int ch = ((4 * kh + quad) ^ (l15 & 7)) << 3;
                a[i]   = *(const bf16x8*)(Xs[buf]  + ra * 64 + ch);
                bfr[i] = *(const bf16x8*)(Ws2[buf] + rb * 64 + ch);
            }
#pragma unroll
            for (int i = 0; i < 4; i++)
#pragma unroll
                for (int j = 0; j < 4; j++)
                    acc[i][j] = __builtin_amdgcn_mfma_f32_16x16x32_bf16(
                        a[i], bfr[j], acc[i][j], 0, 0, 0);
        }
    };

    // prologue: stage slice 0 into buffer 0
    stage(0, 0);
    __syncthreads();

    // main loop, unrolled x2 (768 = 6*128): guarded prefetch, 1 barrier/slice.
    // No DMA in flight at s_endpgm: every stage is consumed by a compute
    // behind a barrier before the kernel ends.
    for (int kt = 0; kt < HH; kt += 128) {
        stage(kt + 64, 1);                       // prefetch odd slice
        compute(0);
        __syncthreads();                         // publishes buf1, frees buf0
        if (kt + 128 < HH) stage(kt + 128, 0);   // prefetch next even slice
        compute(1);
        __syncthreads();                         // publishes buf0, frees buf1
    }

    // Epilogue
#pragma unroll
    for (int i = 0; i < 4; i++) {
        const int m  = m0 + r0 + 16 * i + quad * 4;   // token of r=0
        const int bi = m >> 11;
        const int s0 = m & (SS - 1);
#pragma unroll
        for (int j = 0; j < 4; j++) {
            const int gcol = n0 + c0 + 16 * j + l15;
            const int h = gcol >> 6, d = gcol & 63;
            const float bv_ = bias[gcol];
            const size_t bh = (size_t)(bi * NH + h);
            if (z == 0) {
#pragma unroll
                for (int r = 0; r < 4; r++)
                    Qo[(bh * SS + (s0 + r)) * HD + d] =
                        f2bf((acc[i][j][r] + bv_) * (0.125f * LOG2E));
            } else if (z == 1) {
#pragma unroll
                for (int r = 0; r < 4; r++)
                    Ko[(bh * SS + (s0 + r)) * HD + d] = f2bf(acc[i][j][r] + bv_);
            } else {
                const int s6 = s0 & 63;
                const int kk6 = (s6 & 32) | (((s6 >> 2) & 3) << 3) | (((s6 >> 4) & 1) << 2);
                union { ushort4 u4; fp16x2 h2[2]; } pk;
                pk.h2[0] = __builtin_amdgcn_cvt_pkrtz(acc[i][j][0] + bv_, acc[i][j][1] + bv_);
                pk.h2[1] = __builtin_amdgcn_cvt_pkrtz(acc[i][j][2] + bv_, acc[i][j][3] + bv_);
                *(ushort4*)&Vt[(bh * HD + d) * SS + (s0 & ~63) + kk6] = pk.u4;
            }
        }
    }
}

// ---------------------------------------------------------------------------
// Kernel 2: flash attention. 128 queries/block, 2 q-subtiles/wave.
// Max-free exp2-domain softmax (single v_exp_f32 per score); mask enters as
// the MFMA C-initializer (pre-scaled by log2e, staged once to LDS).
// l_i via MFMA P*ones.  K/V double-buffered via global_load_lds with
// compile-time buffer indices; prefetch guarded (no DMA in flight at endpgm).
// ---------------------------------------------------------------------------
__global__ __launch_bounds__(256) void fattn(
    const ushort* __restrict__ Q, const ushort* __restrict__ K,
    const ushort* __restrict__ Vt, const float* __restrict__ mask,
    float* __restrict__ out)
{
    __shared__ ushort Ks[2][64 * 64];
    __shared__ ushort Vs[2][64 * 64];
    __shared__ float  Ms[SS];      // whole mask row, pre-scaled by log2e

    // XCD-swizzled decode: 768 = 8 xcd * (6 bh * 16 qt)
    const int id = blockIdx.x;
    const int xcd = id & 7, sub = id >> 3;        // sub: 0..95
    const int bh = xcd * 6 + (sub >> 4);          // 0..47
    const int qt = sub & 15;
    const int b = bh / NH, h = bh % NH;

    const int tid = threadIdx.x;
    const int w = tid >> 6, lane = tid & 63, quad = lane >> 4, l15 = lane & 15;
    const int q0 = qt * 128;

    const ushort* Qh = Q  + (size_t)bh * SS * HD;
    const ushort* Kh = K  + (size_t)bh * SS * HD;
    const ushort* Vh = Vt + (size_t)bh * HD * SS;

    // Stage mask row once (scaled to exp2 domain).  2048 floats, 8/thread.
    {
        const float* mrow = mask + (size_t)b * SS;
#pragma unroll
        for (int rep = 0; rep < 2; rep++) {
            const int i = (rep * 256 + tid) * 4;
            float4 mv = *(const float4*)(mrow + i);
            Ms[i + 0] = mv.x * LOG2E; Ms[i + 1] = mv.y * LOG2E;
            Ms[i + 2] = mv.z * LOG2E; Ms[i + 3] = mv.w * LOG2E;
        }
    }

    // Q fragments direct from global (pre-scaled by 0.125*log2e in projection)
    bf16x8 qf[2][2];
#pragma unroll
    for (int qi = 0; qi < 2; qi++)
#pragma unroll
        for (int kh = 0; kh < 2; kh++)
            qf[qi][kh] = *(const bf16x8*)(Qh +
                (size_t)(q0 + 32 * w + 16 * qi + l15) * HD + kh * 32 + quad * 8);

    // staging map (8 rows x 128B per wave-call)
    const int lrow   = lane >> 3;
    const int lchunk = (lane & 7) ^ lrow;
    const ushort* gK = Kh + (size_t)(w * 16 + lrow) * HD + lchunk * 8;
    const ushort* gV = Vh + (size_t)(w * 16 + lrow) * SS + lchunk * 8;

    f32x4 Oa[2][4], accl[2];
#pragma unroll
    for (int qi = 0; qi < 2; qi++) {
        accl[qi] = (f32x4){0.f, 0.f, 0.f, 0.f};
#pragma unroll
        for (int ds = 0; ds < 4; ds++) Oa[qi][ds] = (f32x4){0.f, 0.f, 0.f, 0.f};
    }

    half8 ones;
#pragma unroll
    for (int j = 0; j < 8; j++) ones[j] = (_Float16)1.0f;

    // stage a 64-key tile (K + permuted V) into buffer `buf`
    auto stage = [&](int kt, int buf) {
#pragma unroll
        for (int j = 0; j < 2; j++) {
            __builtin_amdgcn_global_load_lds(
                GLB_CAST(gK + (size_t)kt * HD + (size_t)j * 8 * HD),
                LDS_CAST(Ks[buf] + w * 1024 + j * 512), 16, 0, 0);
            __builtin_amdgcn_global_load_lds(
                GLB_CAST(gV + kt + (size_t)j * 8 * SS),
                LDS_CAST(Vs[buf] + w * 1024 + j * 512), 16, 0, 0);
        }
    };

    // compute one 64-key tile from buffer `buf`
    auto compute = [&](int kt, int buf) {
        // S^T accumulators initialized with the mask (C-init trick)
        f32x4 st[2][4];
#pragma unroll
        for (int t = 0; t < 4; t++) {
            float4 m4 = *(const float4*)&Ms[kt + 16 * t + 4 * quad];
            st[0][t] = (f32x4){m4.x, m4.y, m4.z, m4.w};
            st[1][t] = st[0][t];
        }

        const ushort* Kb = Ks[buf];
#pragma unroll
        for (int t = 0; t < 4; t++) {
            const int row = 16 * t + l15;
            bf16x8 a0 = *(const bf16x8*)(Kb + row * 64 + ((quad ^ (l15 & 7)) << 3));
            bf16x8 a1 = *(const bf16x8*)(Kb + row * 64 + (((4 + quad) ^ (l15 & 7)) << 3));
#pragma unroll
            for (int qi = 0; qi < 2; qi++) {
                st[qi][t] = __builtin_amdgcn_mfma_f32_16x16x32_bf16(a0, qf[qi][0], st[qi][t], 0, 0, 0);
                st[qi][t] = __builtin_amdgcn_mfma_f32_16x16x32_bf16(a1, qf[qi][1], st[qi][t], 0, 0, 0);
            }
        }

        // softmax: p = exp2(min(s, 15.5)), single v_exp_f32; fp16 pack
        union PF { half8 v; fp16x2 h2[4]; } pf[2][2];
#pragma unroll
        for (int qi = 0; qi < 2; qi++) {
            float p[4][4];
#pragma unroll
            for (int t = 0; t < 4; t++)
#pragma unroll
                for (int r = 0; r < 4; r++)
                    p[t][r] = fast_exp2(fminf(st[qi][t][r], 15.5f));
#pragma unroll
            for (int c = 0; c < 2; c++) {
                pf[qi][c].h2[0] = __builtin_amdgcn_cvt_pkrtz(p[2 * c][0], p[2 * c][1]);
                pf[qi][c].h2[1] = __builtin_amdgcn_cvt_pkrtz(p[2 * c][2], p[2 * c][3]);
                pf[qi][c].h2[2] = __builtin_amdgcn_cvt_pkrtz(p[2 * c + 1][0], p[2 * c + 1][1]);
                pf[qi][c].h2[3] = __builtin_amdgcn_cvt_pkrtz(p[2 * c + 1][2], p[2 * c + 1][3]);
            }
        }

        // l += P * ones
#pragma unroll
        for (int qi = 0; qi < 2; qi++) {
            accl[qi] = __builtin_amdgcn_mfma_f32_16x16x32_f16(pf[qi][0].v, ones, accl[qi], 0, 0, 0);
            accl[qi] = __builtin_amdgcn_mfma_f32_16x16x32_f16(pf[qi][1].v, ones, accl[qi], 0, 0, 0);
        }

        // O += P * V
        const ushort* Vb = Vs[buf];
#pragma unroll
        for (int ds = 0; ds < 4; ds++) {
            const int row = 16 * ds + l15;
            half8 v0 = *(const half8*)(Vb + row * 64 + ((quad ^ (l15 & 7)) << 3));
            half8 v1 = *(const half8*)(Vb + row * 64 + (((4 + quad) ^ (l15 & 7)) << 3));
#pragma unroll
            for (int qi = 0; qi < 2; qi++) {
                Oa[qi][ds] = __builtin_amdgcn_mfma_f32_16x16x32_f16(pf[qi][0].v, v0, Oa[qi][ds], 0, 0, 0);
                Oa[qi][ds] = __builtin_amdgcn_mfma_f32_16x16x32_f16(pf[qi][1].v, v1, Oa[qi][ds], 0, 0, 0);
            }
        }
    };

    // prologue: stage tile 0 into buffer 0 (barrier also publishes Ms)
    stage(0, 0);
    __syncthreads();

    // main loop, unrolled x2: compile-time buffer indices, guarded prefetch
    for (int kt = 0; kt < SS; kt += 128) {
        stage(kt + 64, 1);                 // prefetch odd tile
        compute(kt, 0);
        __syncthreads();                   // publishes buf1, frees buf0
        if (kt + 128 < SS) stage(kt + 128, 0);   // prefetch next even tile
        compute(kt + 64, 1);
        __syncthreads();                   // publishes buf0, frees buf1
    }

    // ---- epilogue ----
#pragma unroll
    for (int qi = 0; qi < 2; qi++) {
        float rin[4];
#pragma unroll
        for (int r = 0; r < 4; r++) rin[r] = 1.0f / accl[qi][r];
#pragma unroll
        for (int ds = 0; ds < 4; ds++)
#pragma unroll
            for (int r = 0; r < 4; r++) {
                const int qrow = q0 + 32 * w + 16 * qi + quad * 4 + r;
                out[((size_t)(b * SS + qrow)) * HH + h * HD + ds * 16 + l15] =
                    Oa[qi][ds][r] * rin[r];
            }
    }
}

// ---------------------------------------------------------------------------
extern "C" void kernel_launch(void* const* d_in, const int* in_sizes, int n_in,
                              void* d_out, int out_size, void* d_ws, size_t ws_size,
                              hipStream_t stream) {
    const float* X    = (const float*)d_in[0];
    const float* mask = (const float*)d_in[1];
    const float* Wq   = (const float*)d_in[2];
    const float* bq   = (const float*)d_in[3];
    const float* Wk   = (const float*)d_in[4];
    const float* bk   = (const float*)d_in[5];
    const float* Wv   = (const float*)d_in[6];
    const float* bv   = (const float*)d_in[7];
    float* out = (float*)d_out;

    const size_t NX = (size_t)MROWS * HH;        // 6,291,456
    const size_t NW = (size_t)HH * HH;           //   589,824
    const size_t NQ = (size_t)BB * NH * SS * HD; // 6,291,456

    ushort* Xb  = (ushort*)d_ws;
    ushort* Wqb = Xb + NX;
    ushort* Wkb = Wqb + NW;
    ushort* Wvb = Wkb + NW;
    ushort* Qo  = Wvb + NW;
    ushort* Ko  = Qo + NQ;
    ushort* Vt  = Ko + NQ;

    cvt_kernel<<<3936, 256, 0, stream>>>(X, Wq, Wk, Wv, Xb, Wqb, Wkb, Wvb);

    qkv_mfma<<<1152, 256, 0, stream>>>(Xb, Wqb, Wkb, Wvb, bq, bk, bv, Qo, Ko, Vt);

    fattn<<<768, 256, 0, stream>>>(Qo, Ko, Vt, mask, out);
}

// Round 9
// 198.150 us; speedup vs baseline: 1.0749x; 1.0749x over previous
//
#include <hip/hip_runtime.h>
#include <hip/hip_bf16.h>
#include <math.h>

#define BB 4
#define SS 2048
#define HH 768
#define NH 12
#define HD 64
#define MROWS (BB*SS)   // 8192

typedef __attribute__((ext_vector_type(8))) short bf16x8;
typedef __attribute__((ext_vector_type(4))) float f32x4;
typedef _Float16 half8 __attribute__((ext_vector_type(8)));
typedef __fp16 fp16x2 __attribute__((ext_vector_type(2)));   // cvt_pkrtz result type

#define LDS_CAST(p) ((__attribute__((address_space(3))) void*)(p))
#define GLB_CAST(p) ((const __attribute__((address_space(1))) void*)(p))

#define LOG2E 1.442695040889f

// fast 2^x: single v_exp_f32, NOT the precise OCML exp2f library call
static __device__ __forceinline__ float fast_exp2(float x) {
#if __has_builtin(__builtin_amdgcn_exp2f)
    return __builtin_amdgcn_exp2f(x);
#else
    float r;
    asm("v_exp_f32 %0, %1" : "=v"(r) : "v"(x));
    return r;
#endif
}

static __device__ __forceinline__ ushort f2bf(float f) {
    union { float f; unsigned u; } c; c.f = f;
    unsigned u = c.u;
    return (ushort)((u + 0x7fffu + ((u >> 16) & 1u)) >> 16);
}

// ---------------------------------------------------------------------------
// Kernel 0: fp32 -> bf16 one-shot conversion of X, Wq, Wk, Wv.
// ---------------------------------------------------------------------------
#define XCH  786432u   // 6291456/8
#define WCH  73728u    // 589824/8
__global__ __launch_bounds__(256) void cvt_kernel(
    const float* __restrict__ X,  const float* __restrict__ Wq,
    const float* __restrict__ Wk, const float* __restrict__ Wv,
    ushort* __restrict__ Xb, ushort* __restrict__ Wqb,
    ushort* __restrict__ Wkb, ushort* __restrict__ Wvb)
{
    unsigned c = blockIdx.x * 256 + threadIdx.x;
    const float* src; ushort* dst; size_t idx;
    if (c < XCH) { src = X; dst = Xb; idx = c; }
    else {
        unsigned c2 = c - XCH;
        unsigned w = c2 / WCH, i2 = c2 - w * WCH;
        src = (w == 0) ? Wq : (w == 1) ? Wk : Wv;
        dst = (w == 0) ? Wqb : (w == 1) ? Wkb : Wvb;
        idx = i2;
    }
    size_t e = idx * 8;
    float4 a = *(const float4*)(src + e);
    float4 b = *(const float4*)(src + e + 4);
    unsigned p0 = f2bf(a.x) | ((unsigned)f2bf(a.y) << 16);
    unsigned p1 = f2bf(a.z) | ((unsigned)f2bf(a.w) << 16);
    unsigned p2 = f2bf(b.x) | ((unsigned)f2bf(b.y) << 16);
    unsigned p3 = f2bf(b.z) | ((unsigned)f2bf(b.w) << 16);
    *(int4*)(dst + e) = make_int4((int)p0, (int)p1, (int)p2, (int)p3);
}

// ---------------------------------------------------------------------------
// Kernel 1: QKV projection, 128x128 tile, global_load_lds staging,
// XOR-swizzled LDS.  SINGLE-buffered m97 K-loop (R8's explicit double-buffer
// regressed: 64KB LDS halved resident blocks/CU; implicit multi-block overlap
// at 32KB wins — same lesson as learn_hip m132).
// Q: bf16 [bh][s][d] pre-scaled by 0.125*log2e.  K: bf16 [bh][s][d].
// V: fp16 [bh][d][s], keys pre-permuted within 64-groups.
// ---------------------------------------------------------------------------
__global__ __launch_bounds__(256) void qkv_mfma(
    const ushort* __restrict__ Xb,
    const ushort* __restrict__ Wqb, const ushort* __restrict__ Wkb,
    const ushort* __restrict__ Wvb,
    const float* __restrict__ bq, const float* __restrict__ bk,
    const float* __restrict__ bv,
    ushort* __restrict__ Qo, ushort* __restrict__ Ko, ushort* __restrict__ Vt)
{
    // XCD-swizzled decode: 1152 = 8 xcd * 8 mt * (6 nt * 3 z)
    const int id = blockIdx.x;
    const int xcd = id & 7, sub = id >> 3;        // sub: 0..143
    const int mt = xcd * 8 + (sub & 7);           // 0..63
    const int rest = sub >> 3;                    // 0..17
    const int nt = rest % 6, z = rest / 6;

    const ushort* W    = (z == 0) ? Wqb : (z == 1) ? Wkb : Wvb;
    const float*  bias = (z == 0) ? bq  : (z == 1) ? bk  : bv;

    __shared__ ushort Xs[128 * 64];
    __shared__ ushort Ws2[128 * 64];

    const int tid = threadIdx.x;
    const int w = tid >> 6, lane = tid & 63, quad = lane >> 4, l15 = lane & 15;
    const int m0 = mt * 128, n0 = nt * 128;
    const int r0 = (w >> 1) * 64, c0 = (w & 1) * 64;

    const int lrow   = lane >> 3;                 // 0..7
    const int lchunk = (lane & 7) ^ lrow;         // logical 16B-chunk
    const ushort* gX = Xb + (size_t)(m0 + w * 32 + lrow) * HH + lchunk * 8;
    const ushort* gW = W  + (size_t)(n0 + w * 32 + lrow) * HH + lchunk * 8;
    ushort* ldsX = Xs  + w * 2048;
    ushort* ldsW = Ws2 + w * 2048;

    f32x4 acc[4][4];
#pragma unroll
    for (int i = 0; i < 4; i++)
#pragma unroll
        for (int j = 0; j < 4; j++) acc[i][j] = (f32x4){0.f, 0.f, 0.f, 0.f};

    for (int kt = 0; kt < HH; kt += 64) {
        __syncthreads();
        const ushort* gx = gX + kt;
        const ushort* gw = gW + kt;
#pragma unroll
        for (int j = 0; j < 4; j++) {
            __builtin_amdgcn_global_load_lds(GLB_CAST(gx + (size_t)j * 8 * HH),
                                             LDS_CAST(ldsX + j * 512), 16, 0, 0);
            __builtin_amdgcn_global_load_lds(GLB_CAST(gw + (size_t)j * 8 * HH),
                                             LDS_CAST(ldsW + j * 512), 16, 0, 0);
        }
        __syncthreads();
#pragma unroll
        for (int kh = 0; kh < 2; kh++) {
            bf16x8 a[4], bfr[4];
#pragma unroll
            for (int i = 0; i < 4; i++) {
                const int ra = r0 + 16 * i + l15;
                const int rb = c0 + 16 * i + l15;
                const int ch = ((4 * kh + quad) ^ (l15 & 7)) << 3;
                a[i]   = *(const bf16x8*)(Xs  + ra * 64 + ch);
                bfr[i] = *(const bf16x8*)(Ws2 + rb * 64 + ch);
            }
#pragma unroll
            for (int i = 0; i < 4; i++)
#pragma unroll
                for (int j = 0; j < 4; j++)
                    acc[i][j] = __builtin_amdgcn_mfma_f32_16x16x32_bf16(
                        a[i], bfr[j], acc[i][j], 0, 0, 0);
        }
    }

    // Epilogue
#pragma unroll
    for (int i = 0; i < 4; i++) {
        const int m  = m0 + r0 + 16 * i + quad * 4;   // token of r=0
        const int bi = m >> 11;
        const int s0 = m & (SS - 1);
#pragma unroll
        for (int j = 0; j < 4; j++) {
            const int gcol = n0 + c0 + 16 * j + l15;
            const int h = gcol >> 6, d = gcol & 63;
            const float bv_ = bias[gcol];
            const size_t bh = (size_t)(bi * NH + h);
            if (z == 0) {
#pragma unroll
                for (int r = 0; r < 4; r++)
                    Qo[(bh * SS + (s0 + r)) * HD + d] =
                        f2bf((acc[i][j][r] + bv_) * (0.125f * LOG2E));
            } else if (z == 1) {
#pragma unroll
                for (int r = 0; r < 4; r++)
                    Ko[(bh * SS + (s0 + r)) * HD + d] = f2bf(acc[i][j][r] + bv_);
            } else {
                const int s6 = s0 & 63;
                const int kk6 = (s6 & 32) | (((s6 >> 2) & 3) << 3) | (((s6 >> 4) & 1) << 2);
                union { ushort4 u4; fp16x2 h2[2]; } pk;
                pk.h2[0] = __builtin_amdgcn_cvt_pkrtz(acc[i][j][0] + bv_, acc[i][j][1] + bv_);
                pk.h2[1] = __builtin_amdgcn_cvt_pkrtz(acc[i][j][2] + bv_, acc[i][j][3] + bv_);
                *(ushort4*)&Vt[(bh * HD + d) * SS + (s0 & ~63) + kk6] = pk.u4;
            }
        }
    }
}

// ---------------------------------------------------------------------------
// Kernel 2: flash attention. 128 queries/block, 2 q-subtiles/wave.
// Max-free exp2-domain softmax; clamp REMOVED: v_cvt_pkrtz rounds toward
// zero, so finite f32 overflow saturates to max-finite fp16 — the fmin was
// redundant (saves 32 VALU insts/tile in the dominant pipe).
// Mask enters as the MFMA C-initializer.  l_i via MFMA P*ones.
// K/V double-buffered via global_load_lds, guarded prefetch.
// ---------------------------------------------------------------------------
__global__ __launch_bounds__(256) void fattn(
    const ushort* __restrict__ Q, const ushort* __restrict__ K,
    const ushort* __restrict__ Vt, const float* __restrict__ mask,
    float* __restrict__ out)
{
    __shared__ ushort Ks[2][64 * 64];
    __shared__ ushort Vs[2][64 * 64];
    __shared__ float  Ms[SS];      // whole mask row, pre-scaled by log2e

    // XCD-swizzled decode: 768 = 8 xcd * (6 bh * 16 qt)
    const int id = blockIdx.x;
    const int xcd = id & 7, sub = id >> 3;        // sub: 0..95
    const int bh = xcd * 6 + (sub >> 4);          // 0..47
    const int qt = sub & 15;
    const int b = bh / NH, h = bh % NH;

    const int tid = threadIdx.x;
    const int w = tid >> 6, lane = tid & 63, quad = lane >> 4, l15 = lane & 15;
    const int q0 = qt * 128;

    const ushort* Qh = Q  + (size_t)bh * SS * HD;
    const ushort* Kh = K  + (size_t)bh * SS * HD;
    const ushort* Vh = Vt + (size_t)bh * HD * SS;

    // Stage mask row once (scaled to exp2 domain).  2048 floats, 8/thread.
    {
        const float* mrow = mask + (size_t)b * SS;
#pragma unroll
        for (int rep = 0; rep < 2; rep++) {
            const int i = (rep * 256 + tid) * 4;
            float4 mv = *(const float4*)(mrow + i);
            Ms[i + 0] = mv.x * LOG2E; Ms[i + 1] = mv.y * LOG2E;
            Ms[i + 2] = mv.z * LOG2E; Ms[i + 3] = mv.w * LOG2E;
        }
    }

    // Q fragments direct from global (pre-scaled by 0.125*log2e in projection)
    bf16x8 qf[2][2];
#pragma unroll
    for (int qi = 0; qi < 2; qi++)
#pragma unroll
        for (int kh = 0; kh < 2; kh++)
            qf[qi][kh] = *(const bf16x8*)(Qh +
                (size_t)(q0 + 32 * w + 16 * qi + l15) * HD + kh * 32 + quad * 8);

    // staging map (8 rows x 128B per wave-call)
    const int lrow   = lane >> 3;
    const int lchunk = (lane & 7) ^ lrow;
    const ushort* gK = Kh + (size_t)(w * 16 + lrow) * HD + lchunk * 8;
    const ushort* gV = Vh + (size_t)(w * 16 + lrow) * SS + lchunk * 8;

    f32x4 Oa[2][4], accl[2];
#pragma unroll
    for (int qi = 0; qi < 2; qi++) {
        accl[qi] = (f32x4){0.f, 0.f, 0.f, 0.f};
#pragma unroll
        for (int ds = 0; ds < 4; ds++) Oa[qi][ds] = (f32x4){0.f, 0.f, 0.f, 0.f};
    }

    half8 ones;
#pragma unroll
    for (int j = 0; j < 8; j++) ones[j] = (_Float16)1.0f;

    // stage a 64-key tile (K + permuted V) into buffer `buf`
    auto stage = [&](int kt, int buf) {
#pragma unroll
        for (int j = 0; j < 2; j++) {
            __builtin_amdgcn_global_load_lds(
                GLB_CAST(gK + (size_t)kt * HD + (size_t)j * 8 * HD),
                LDS_CAST(Ks[buf] + w * 1024 + j * 512), 16, 0, 0);
            __builtin_amdgcn_global_load_lds(
                GLB_CAST(gV + kt + (size_t)j * 8 * SS),
                LDS_CAST(Vs[buf] + w * 1024 + j * 512), 16, 0, 0);
        }
    };

    // compute one 64-key tile from buffer `buf`
    auto compute = [&](int kt, int buf) {
        // S^T accumulators initialized with the mask (C-init trick)
        f32x4 st[2][4];
#pragma unroll
        for (int t = 0; t < 4; t++) {
            float4 m4 = *(const float4*)&Ms[kt + 16 * t + 4 * quad];
            st[0][t] = (f32x4){m4.x, m4.y, m4.z, m4.w};
            st[1][t] = st[0][t];
        }

        const ushort* Kb = Ks[buf];
#pragma unroll
        for (int t = 0; t < 4; t++) {
            const int row = 16 * t + l15;
            bf16x8 a0 = *(const bf16x8*)(Kb + row * 64 + ((quad ^ (l15 & 7)) << 3));
            bf16x8 a1 = *(const bf16x8*)(Kb + row * 64 + (((4 + quad) ^ (l15 & 7)) << 3));
#pragma unroll
            for (int qi = 0; qi < 2; qi++) {
                st[qi][t] = __builtin_amdgcn_mfma_f32_16x16x32_bf16(a0, qf[qi][0], st[qi][t], 0, 0, 0);
                st[qi][t] = __builtin_amdgcn_mfma_f32_16x16x32_bf16(a1, qf[qi][1], st[qi][t], 0, 0, 0);
            }
        }

        // softmax: p = exp2(s); fp16 pack (pkrtz saturates — no clamp needed)
        union PF { half8 v; fp16x2 h2[4]; } pf[2][2];
#pragma unroll
        for (int qi = 0; qi < 2; qi++) {
            float p[4][4];
#pragma unroll
            for (int t = 0; t < 4; t++)
#pragma unroll
                for (int r = 0; r < 4; r++)
                    p[t][r] = fast_exp2(st[qi][t][r]);
#pragma unroll
            for (int c = 0; c < 2; c++) {
                pf[qi][c].h2[0] = __builtin_amdgcn_cvt_pkrtz(p[2 * c][0], p[2 * c][1]);
                pf[qi][c].h2[1] = __builtin_amdgcn_cvt_pkrtz(p[2 * c][2], p[2 * c][3]);
                pf[qi][c].h2[2] = __builtin_amdgcn_cvt_pkrtz(p[2 * c + 1][0], p[2 * c + 1][1]);
                pf[qi][c].h2[3] = __builtin_amdgcn_cvt_pkrtz(p[2 * c + 1][2], p[2 * c + 1][3]);
            }
        }

        // l += P * ones
#pragma unroll
        for (int qi = 0; qi < 2; qi++) {
            accl[qi] = __builtin_amdgcn_mfma_f32_16x16x32_f16(pf[qi][0].v, ones, accl[qi], 0, 0, 0);
            accl[qi] = __builtin_amdgcn_mfma_f32_16x16x32_f16(pf[qi][1].v, ones, accl[qi], 0, 0, 0);
        }

        // O += P * V
        const ushort* Vb = Vs[buf];
#pragma unroll
        for (int ds = 0; ds < 4; ds++) {
            const int row = 16 * ds + l15;
            half8 v0 = *(const half8*)(Vb + row * 64 + ((quad ^ (l15 & 7)) << 3));
            half8 v1 = *(const half8*)(Vb + row * 64 + (((4 + quad) ^ (l15 & 7)) << 3));
#pragma unroll
            for (int qi = 0; qi < 2; qi++) {
                Oa[qi][ds] = __builtin_amdgcn_mfma_f32_16x16x32_f16(pf[qi][0].v, v0, Oa[qi][ds], 0, 0, 0);
                Oa[qi][ds] = __builtin_amdgcn_mfma_f32_16x16x32_f16(pf[qi][1].v, v1, Oa[qi][ds], 0, 0, 0);
            }
        }
    };

    // prologue: stage tile 0 into buffer 0 (barrier also publishes Ms)
    stage(0, 0);
    __syncthreads();

    // main loop, unrolled x2: compile-time buffer indices, guarded prefetch
    // (no DMA in flight at s_endpgm — LDS use-after-free race, fixed R6)
    for (int kt = 0; kt < SS; kt += 128) {
        stage(kt + 64, 1);                 // prefetch odd tile
        compute(kt, 0);
        __syncthreads();                   // publishes buf1, frees buf0
        if (kt + 128 < SS) stage(kt + 128, 0);   // prefetch next even tile
        compute(kt + 64, 1);
        __syncthreads();                   // publishes buf0, frees buf1
    }

    // ---- epilogue ----
#pragma unroll
    for (int qi = 0; qi < 2; qi++) {
        float rin[4];
#pragma unroll
        for (int r = 0; r < 4; r++) rin[r] = 1.0f / accl[qi][r];
#pragma unroll
        for (int ds = 0; ds < 4; ds++)
#pragma unroll
            for (int r = 0; r < 4; r++) {
                const int qrow = q0 + 32 * w + 16 * qi + quad * 4 + r;
                out[((size_t)(b * SS + qrow)) * HH + h * HD + ds * 16 + l15] =
                    Oa[qi][ds][r] * rin[r];
            }
    }
}

// ---------------------------------------------------------------------------
extern "C" void kernel_launch(void* const* d_in, const int* in_sizes, int n_in,
                              void* d_out, int out_size, void* d_ws, size_t ws_size,
                              hipStream_t stream) {
    const float* X    = (const float*)d_in[0];
    const float* mask = (const float*)d_in[1];
    const float* Wq   = (const float*)d_in[2];
    const float* bq   = (const float*)d_in[3];
    const float* Wk   = (const float*)d_in[4];
    const float* bk   = (const float*)d_in[5];
    const float* Wv   = (const float*)d_in[6];
    const float* bv   = (const float*)d_in[7];
    float* out = (float*)d_out;

    const size_t NX = (size_t)MROWS * HH;        // 6,291,456
    const size_t NW = (size_t)HH * HH;           //   589,824
    const size_t NQ = (size_t)BB * NH * SS * HD; // 6,291,456

    ushort* Xb  = (ushort*)d_ws;
    ushort* Wqb = Xb + NX;
    ushort* Wkb = Wqb + NW;
    ushort* Wvb = Wkb + NW;
    ushort* Qo  = Wvb + NW;
    ushort* Ko  = Qo + NQ;
    ushort* Vt  = Ko + NQ;

    cvt_kernel<<<3936, 256, 0, stream>>>(X, Wq, Wk, Wv, Xb, Wqb, Wkb, Wvb);

    qkv_mfma<<<1152, 256, 0, stream>>>(Xb, Wqb, Wkb, Wvb, bq, bk, bv, Qo, Ko, Vt);

    fattn<<<768, 256, 0, stream>>>(Qo, Ko, Vt, mask, out);
}